// Round 8
// baseline (274.887 us; speedup 1.0000x reference)
//
#include <hip/hip_runtime.h>
#include <hip/hip_bf16.h>

typedef __bf16 bf16x8 __attribute__((ext_vector_type(8)));
typedef float f32x4 __attribute__((ext_vector_type(4)));

using bf = __hip_bfloat16;

constexpr int cB = 16, cH = 96, cW = 96, cC = 192;
constexpr int cT = cH * cW;       // 9216
constexpr int cM = cB * cT;       // 147456
constexpr int CH = 48;            // wkv chunk length
constexpr int NS = cT / CH;       // 192 chunks
constexpr float Tinv = 1.0f / 9216.0f;

__device__ __forceinline__ int swz(int row, int bytecol) {
    return row * 384 + (bytecol ^ ((row & 7) << 4));
}
__device__ __forceinline__ float bflo(unsigned u) { return __uint_as_float(u << 16); }
__device__ __forceinline__ float bfhi(unsigned u) { return __uint_as_float(u & 0xffff0000u); }

// ---------------------------------------------------------------------------
// Pre-convert weights f32 -> bf16, concatenated rows: [Wk;Wv;Wr;Wo] (768x192)
// ---------------------------------------------------------------------------
__global__ __launch_bounds__(256) void convw_k(
    const float* __restrict__ Wk, const float* __restrict__ Wv,
    const float* __restrict__ Wr, const float* __restrict__ Wo,
    bf* __restrict__ out)
{
    int i = (blockIdx.x * 256 + threadIdx.x) * 8;
    int mat = i / 36864, off = i % 36864;
    const float* s = mat == 0 ? Wk : (mat == 1 ? Wv : (mat == 2 ? Wr : Wo));
    const float4* sp = reinterpret_cast<const float4*>(s + off);
    float4 a0 = sp[0], a1 = sp[1];
    bf16x8 pk;
    pk[0]=(__bf16)a0.x; pk[1]=(__bf16)a0.y; pk[2]=(__bf16)a0.z; pk[3]=(__bf16)a0.w;
    pk[4]=(__bf16)a1.x; pk[5]=(__bf16)a1.y; pk[6]=(__bf16)a1.z; pk[7]=(__bf16)a1.w;
    *reinterpret_cast<bf16x8*>(reinterpret_cast<__bf16*>(out) + i) = pk;
}

// ---------------------------------------------------------------------------
// Persistent depth-2 pipelined GEMM. 256 blocks (1/CU), 512 thr (8 waves 2mx4n).
// LDS: A triple-buffer 3x24KB + full B matrix 72KB = 144KB.
// Step i: compute buf[i%3] | store | ds_write pf(tile i+1) -> buf[(i+1)%3] |
//         issue loads tile(i+2) | barrier.   (loads get a full step to land)
// MODE 0: A = x(f32)+2D shift, 1 mat (Wk) -> k bf16 [m][c]; ALSO writes the
//         shifted bf16 A rows to xs (O1) for reuse by MODE 2.
// MODE 2: A = xs(bf16), 2 mats (Wv,Wr) -> v, sigmoid(r).
// MODE 1: A = z(bf16), 1 mat (Wo) -> out f32.
// ---------------------------------------------------------------------------
template <int MODE>
__global__ __launch_bounds__(512, 2) void gemm_k(
    const void* __restrict__ Ap, const bf* __restrict__ Wb,
    void* __restrict__ O0, void* __restrict__ O1, void* __restrict__ O2)
{
    constexpr int NMAT = (MODE == 2) ? 2 : 1;
    __shared__ char lds[3 * 64 * 384 + 192 * 384];
    const int tid = threadIdx.x, bx = blockIdx.x;
    const int lane = tid & 63, wid = tid >> 6;
    const int wm = wid >> 2, wn = wid & 3;   // 2m x 4n waves: 32 x 48 each
    const int lr = lane & 15, lq = lane >> 4;

    int rj[3], kbj[3];
#pragma unroll
    for (int j = 0; j < 3; ++j) { int idx = tid + j * 512; rj[j] = idx / 24; kbj[j] = idx % 24; }

    float4 pfA[6], pfB[6];
    int4   piA[3], piB[3];

    auto loadTile = [&](int tile, float4* pf, int4* pi) {
        if constexpr (MODE == 0) {
            const float* Af = (const float*)Ap;
#pragma unroll
            for (int j = 0; j < 3; ++j) {
                int gm = tile * 64 + rj[j];
                int b = gm / cT, t = gm % cT, h = t / cW, w = t % cW;
                int grp = kbj[j] / 6;
                int hs = h + (grp == 2 ? -1 : (grp == 3 ? 1 : 0));
                int ws2 = w + (grp == 0 ? -1 : (grp == 1 ? 1 : 0));
                pf[2*j] = float4{0,0,0,0}; pf[2*j+1] = float4{0,0,0,0};
                if (hs >= 0 && hs < cH && ws2 >= 0 && ws2 < cW) {
                    const float4* s = reinterpret_cast<const float4*>(
                        Af + ((size_t)b * cT + (size_t)hs * cW + ws2) * cC + kbj[j] * 8);
                    pf[2*j] = s[0]; pf[2*j+1] = s[1];
                }
            }
        } else {
            const bf* Az = (const bf*)Ap;
#pragma unroll
            for (int j = 0; j < 3; ++j)
                pi[j] = *reinterpret_cast<const int4*>(
                    Az + (size_t)(tile * 64 + rj[j]) * cC + kbj[j] * 8);
        }
    };
    auto writeTile = [&](int bufIdx, int tile, float4* pf, int4* pi) {
        char* An = &lds[0] + bufIdx * (64 * 384);
        if constexpr (MODE == 0) {
            bf* Xs = (bf*)O1;
#pragma unroll
            for (int j = 0; j < 3; ++j) {
                bf16x8 pk;
                pk[0]=(__bf16)pf[2*j].x; pk[1]=(__bf16)pf[2*j].y; pk[2]=(__bf16)pf[2*j].z; pk[3]=(__bf16)pf[2*j].w;
                pk[4]=(__bf16)pf[2*j+1].x; pk[5]=(__bf16)pf[2*j+1].y; pk[6]=(__bf16)pf[2*j+1].z; pk[7]=(__bf16)pf[2*j+1].w;
                *reinterpret_cast<bf16x8*>(An + swz(rj[j], kbj[j] * 16)) = pk;
                *reinterpret_cast<bf16x8*>(Xs + (size_t)(tile * 64 + rj[j]) * cC + kbj[j] * 8) = pk;
            }
        } else {
#pragma unroll
            for (int j = 0; j < 3; ++j)
                *reinterpret_cast<int4*>(An + swz(rj[j], kbj[j] * 16)) = pi[j];
        }
    };

    for (int mat = 0; mat < NMAT; ++mat) {
        // ---- stage B: full 192x192 bf16 matrix, swizzled ----
        {
            const bf* Wt = Wb + (size_t)mat * 192 * cC;
            char* Bb = &lds[0] + 3 * 64 * 384;
            for (int it = 0; it < 9; ++it) {
                int idx = tid + it * 512;
                int r = idx / 24, kb = idx % 24;
                int4 val = *reinterpret_cast<const int4*>(Wt + r * cC + kb * 8);
                *reinterpret_cast<int4*>(Bb + swz(r, kb * 16)) = val;
            }
        }
        // ---- prologue: tile0 -> buf0; issue tile1 loads ----
        loadTile(bx, pfA, piA);
        writeTile(0, bx, pfA, piA);
        loadTile(bx + 256, pfB, piB);
        __syncthreads();

        auto step = [&](int i, float4* wrF, int4* wrI, float4* ldF, int4* ldI) {
            char* Ab = &lds[0] + (i % 3) * (64 * 384);
            char* Bb = &lds[0] + 3 * 64 * 384;
            f32x4 acc[2][3] = {};
#pragma unroll
            for (int kk = 0; kk < 6; ++kk) {
                const int bc = kk * 64 + lq * 16;
                bf16x8 af[2], bfr[3];
#pragma unroll
                for (int mt = 0; mt < 2; ++mt)
                    af[mt] = *reinterpret_cast<const bf16x8*>(Ab + swz(wm * 32 + mt * 16 + lr, bc));
#pragma unroll
                for (int nt = 0; nt < 3; ++nt)
                    bfr[nt] = *reinterpret_cast<const bf16x8*>(Bb + swz(wn * 48 + nt * 16 + lr, bc));
#pragma unroll
                for (int mt = 0; mt < 2; ++mt)
#pragma unroll
                    for (int nt = 0; nt < 3; ++nt)
                        acc[mt][nt] = __builtin_amdgcn_mfma_f32_16x16x32_bf16(
                            af[mt], bfr[nt], acc[mt][nt], 0, 0, 0);
            }
            const int tix = bx + 256 * i;
            if constexpr (MODE == 1) {
                float* Os = (float*)O0;
#pragma unroll
                for (int mt = 0; mt < 2; ++mt)
#pragma unroll
                    for (int nt = 0; nt < 3; ++nt)
#pragma unroll
                        for (int j = 0; j < 4; ++j) {
                            int row = tix * 64 + wm * 32 + mt * 16 + lq * 4 + j;
                            int col = wn * 48 + nt * 16 + lr;
                            Os[(size_t)row * cC + col] = acc[mt][nt][j];
                        }
            } else {
                const bool sig = (MODE == 2) && (mat == 1);
                bf* Os = (bf*)((MODE == 0) ? O0 : (mat == 0 ? O0 : O1));
#pragma unroll
                for (int mt = 0; mt < 2; ++mt)
#pragma unroll
                    for (int nt = 0; nt < 3; ++nt)
#pragma unroll
                        for (int j = 0; j < 4; ++j) {
                            int row = tix * 64 + wm * 32 + mt * 16 + lq * 4 + j;
                            int col = wn * 48 + nt * 16 + lr;
                            float v = acc[mt][nt][j];
                            if (sig) v = 1.0f / (1.0f + __expf(-v));
                            Os[(size_t)row * cC + col] = __float2bfloat16(v);
                        }
            }
            if (i < 8) writeTile((i + 1) % 3, bx + 256 * (i + 1), wrF, wrI);
            if (i < 7) loadTile(bx + 256 * (i + 2), ldF, ldI);
            __syncthreads();
        };

        for (int ii = 0; ii < 4; ++ii) {
            step(2 * ii,     pfB, piB, pfA, piA);
            step(2 * ii + 1, pfA, piA, pfB, piB);
        }
        step(8, pfB, piB, pfA, piA);
    }
}

// ---------------------------------------------------------------------------
// WKV chunked scan over [m][c] bf16, 2 channels/thread, CH=48 (NS=192 chunks),
// per-step software prefetch. State: true numerator = p*e^o, denom = q*e^o.
// ---------------------------------------------------------------------------
__global__ __launch_bounds__(192) void wkv_pass1(
    const bf* __restrict__ k, const bf* __restrict__ v,
    const float* __restrict__ sd,
    float* __restrict__ stP, float* __restrict__ stQ, float* __restrict__ stO)
{
    const int c2 = threadIdx.x % 96, sub = threadIdx.x / 96;
    const int b = blockIdx.y, ch = blockIdx.x * 2 + sub;
    const int c0 = c2 * 2;
    const float w0 = sd[c0] * Tinv, w1 = sd[c0 + 1] * Tinv;
    size_t base = ((size_t)b * cT + (size_t)ch * CH) * cC + c0;
    float p0 = 0.f, q0 = 0.f, o0 = -1e38f;
    float p1 = 0.f, q1 = 0.f, o1 = -1e38f;
    unsigned kwc = *reinterpret_cast<const unsigned*>(k + base);
    unsigned vwc = *reinterpret_cast<const unsigned*>(v + base);
    for (int s = 0; s < CH; ++s) {
        unsigned kwn = 0, vwn = 0;
        if (s + 1 < CH) {
            kwn = *reinterpret_cast<const unsigned*>(k + base + (size_t)(s + 1) * cC);
            vwn = *reinterpret_cast<const unsigned*>(v + base + (size_t)(s + 1) * cC);
        }
        float kt0 = bflo(kwc), kt1 = bfhi(kwc);
        float vt0 = bflo(vwc), vt1 = bfhi(vwc);
        float no0 = fmaxf(w0 + o0, kt0);
        float A0 = __expf(w0 + o0 - no0), B0 = __expf(kt0 - no0);
        p0 = A0 * p0 + B0 * vt0; q0 = A0 * q0 + B0; o0 = no0;
        float no1 = fmaxf(w1 + o1, kt1);
        float A1 = __expf(w1 + o1 - no1), B1 = __expf(kt1 - no1);
        p1 = A1 * p1 + B1 * vt1; q1 = A1 * q1 + B1; o1 = no1;
        kwc = kwn; vwc = vwn;
    }
    size_t si = ((size_t)b * NS + ch) * cC + c0;
    *reinterpret_cast<float2*>(stP + si) = make_float2(p0, p1);
    *reinterpret_cast<float2*>(stQ + si) = make_float2(q0, q1);
    *reinterpret_cast<float2*>(stO + si) = make_float2(o0, o1);
}

// In-place: overwrites stP/stQ/stO with the EXCLUSIVE prefix state.
__global__ __launch_bounds__(192) void wkv_pass2(
    float* __restrict__ stP, float* __restrict__ stQ, float* __restrict__ stO,
    const float* __restrict__ sd)
{
    const int c = threadIdx.x, b = blockIdx.x;
    const float w = sd[c] * Tinv;
    const float Lw = w * (float)CH;
    float p = 0.f, q = 0.f, o = -1e38f;
    size_t si = (size_t)b * NS * cC + c;
    float sp = stP[si], sq = stQ[si], so = stO[si];
    for (int ch = 0; ch < NS; ++ch) {
        float np_ = 0.f, nq_ = 0.f, no_ = -1e38f;
        if (ch + 1 < NS) {
            size_t sj = si + (size_t)(ch + 1) * cC;
            np_ = stP[sj]; nq_ = stQ[sj]; no_ = stO[sj];
        }
        size_t sc = si + (size_t)ch * cC;
        stP[sc] = p; stQ[sc] = q; stO[sc] = o;   // exclusive prefix (in place)
        float po = o + Lw;
        float m = fmaxf(po, so);
        float e1 = __expf(po - m), e2 = __expf(so - m);
        p = e1 * p + e2 * sp;
        q = e1 * q + e2 * sq;
        o = m;
        sp = np_; sq = nq_; so = no_;
    }
}

__global__ __launch_bounds__(192) void wkv_pass3(
    const bf* __restrict__ k, const bf* __restrict__ v, const bf* __restrict__ sr,
    const float* __restrict__ sd, const float* __restrict__ sf,
    const float* __restrict__ iP, const float* __restrict__ iQ,
    const float* __restrict__ iO, bf* __restrict__ z)
{
    const int c2 = threadIdx.x % 96, sub = threadIdx.x / 96;
    const int b = blockIdx.y, ch = blockIdx.x * 2 + sub;
    const int c0 = c2 * 2;
    const float w0 = sd[c0] * Tinv, w1 = sd[c0 + 1] * Tinv;
    const float u0 = sf[c0] * Tinv, u1 = sf[c0 + 1] * Tinv;
    size_t si = ((size_t)b * NS + ch) * cC + c0;
    float2 pp = *reinterpret_cast<const float2*>(iP + si);
    float2 qq = *reinterpret_cast<const float2*>(iQ + si);
    float2 oo = *reinterpret_cast<const float2*>(iO + si);
    float p0 = pp.x, q0 = qq.x, o0 = oo.x;
    float p1 = pp.y, q1 = qq.y, o1 = oo.y;
    size_t base = ((size_t)b * cT + (size_t)ch * CH) * cC + c0;
    unsigned kwc = *reinterpret_cast<const unsigned*>(k + base);
    unsigned vwc = *reinterpret_cast<const unsigned*>(v + base);
    unsigned rwc = *reinterpret_cast<const unsigned*>(sr + base);
    for (int s = 0; s < CH; ++s) {
        unsigned kwn = 0, vwn = 0, rwn = 0;
        if (s + 1 < CH) {
            size_t nx = base + (size_t)(s + 1) * cC;
            kwn = *reinterpret_cast<const unsigned*>(k + nx);
            vwn = *reinterpret_cast<const unsigned*>(v + nx);
            rwn = *reinterpret_cast<const unsigned*>(sr + nx);
        }
        float kt0 = bflo(kwc), kt1 = bfhi(kwc);
        float vt0 = bflo(vwc), vt1 = bfhi(vwc);
        float rt0 = bflo(rwc), rt1 = bfhi(rwc);

        float no0 = fmaxf(o0, u0 + kt0);
        float Ae0 = __expf(o0 - no0), Be0 = __expf(u0 + kt0 - no0);
        float y0 = (Ae0 * p0 + Be0 * vt0) / (Ae0 * q0 + Be0);
        float no1 = fmaxf(o1, u1 + kt1);
        float Ae1 = __expf(o1 - no1), Be1 = __expf(u1 + kt1 - no1);
        float y1 = (Ae1 * p1 + Be1 * vt1) / (Ae1 * q1 + Be1);

        bf z0 = __float2bfloat16(rt0 * y0);
        bf z1 = __float2bfloat16(rt1 * y1);
        unsigned zp = (unsigned)*reinterpret_cast<unsigned short*>(&z0)
                    | ((unsigned)*reinterpret_cast<unsigned short*>(&z1) << 16);
        *reinterpret_cast<unsigned*>(z + base + (size_t)s * cC) = zp;

        float m0 = fmaxf(w0 + o0, kt0);
        float A0 = __expf(w0 + o0 - m0), B0 = __expf(kt0 - m0);
        p0 = A0 * p0 + B0 * vt0; q0 = A0 * q0 + B0; o0 = m0;
        float m1 = fmaxf(w1 + o1, kt1);
        float A1 = __expf(w1 + o1 - m1), B1 = __expf(kt1 - m1);
        p1 = A1 * p1 + B1 * vt1; q1 = A1 * q1 + B1; o1 = m1;
        kwc = kwn; vwc = vwn; rwc = rwn;
    }
}

extern "C" void kernel_launch(void* const* d_in, const int* in_sizes, int n_in,
                              void* d_out, int out_size, void* d_ws, size_t ws_size,
                              hipStream_t stream)
{
    const float* x  = (const float*)d_in[0];
    const float* Wk = (const float*)d_in[1];
    const float* Wv = (const float*)d_in[2];
    const float* Wr = (const float*)d_in[3];
    const float* Wo = (const float*)d_in[4];
    const float* sd = (const float*)d_in[5];
    const float* sf = (const float*)d_in[6];
    float* out = (float*)d_out;

    const size_t nEl = (size_t)cM * cC;          // 28,311,552 elements
    // d_out (f32, 113.2MB) holds k and sr (bf16, 2x56.6MB) until gemm1.
    bf* kbuf  = (bf*)d_out;
    bf* srbuf = (bf*)d_out + nEl;
    char* ws = (char*)d_ws;
    bf* vbuf = (bf*)ws;                           // 56.6MB
    bf* xsbuf = (bf*)(ws + 2 * nEl);              // 56.6MB: shifted-x bf16; later reused as z
    bf* zbuf = xsbuf;                             // z overwrites xs (xs dead after gemm<2>)
    const size_t stN = (size_t)cB * NS * cC;      // 589,824 floats each
    float* stP = (float*)(ws + 4 * nEl);          // 3 x 2.36MB (in-place prefix in pass2)
    float* stQ = stP + stN;
    float* stO = stQ + stN;
    bf* wbf = (bf*)(stO + stN);                   // [Wk;Wv;Wr;Wo] bf16, 768x192

    convw_k<<<dim3(72), dim3(256), 0, stream>>>(Wk, Wv, Wr, Wo, wbf);
    gemm_k<0><<<dim3(256), dim3(512), 0, stream>>>(x, wbf, kbuf, xsbuf, nullptr);
    gemm_k<2><<<dim3(256), dim3(512), 0, stream>>>(
        xsbuf, wbf + (size_t)192 * cC, vbuf, srbuf, nullptr);
    wkv_pass1<<<dim3(NS / 2, cB), dim3(192), 0, stream>>>(kbuf, vbuf, sd, stP, stQ, stO);
    wkv_pass2<<<dim3(cB), dim3(192), 0, stream>>>(stP, stQ, stO, sd);
    wkv_pass3<<<dim3(NS / 2, cB), dim3(192), 0, stream>>>(
        kbuf, vbuf, srbuf, sd, sf, stP, stQ, stO, zbuf);
    gemm_k<1><<<dim3(256), dim3(512), 0, stream>>>(
        zbuf, wbf + (size_t)576 * cC, out, nullptr, nullptr);
}